// Round 7
// baseline (100.868 us; speedup 1.0000x reference)
//
#include <hip/hip_runtime.h>

// n = 8192 points, d = 512, fp32 in, scalar fp32 out.
// Pipeline:
//   (1) fp32 -> fp8 e4m3 convert (+ zero-init packed argmax keys)
//   (2) triangular fused fp8-MFMA GEMM, "mega-stage" schedule: per 128x128
//       tile-pair block, stage a full K-half (64 KB) at once, hoist ALL
//       fragment ds_reads, then run 128 barrier-free MFMAs while the next
//       half's stage is in flight. 2 sync points per block (vs 16).
//       2 blocks/CU hide each other's cold stage. Dual row/col argmax via
//       deterministic u64 atomicMax of (monotone(value)<<32 | ~index).
//   (3) per-row ||x - x[I] + 1e-6||_2 -> log   (full fp32)
//   (4) deterministic mean reduce.

#define NPTS 8192
#define DIM  512
#define BM   128
#define BN   128
#define NTIL 64
#define NBLK (NTIL * (NTIL + 1) / 2)   // 2080 (= 8*260, XCD-divisible)

typedef float f32x4 __attribute__((ext_vector_type(4)));
typedef long  lx2   __attribute__((ext_vector_type(2)));   // 16 B

// f32 -> OCP e4m3fn, round-to-nearest-even; N(0,1) data never clamps.
__device__ __forceinline__ unsigned char f32_to_e4m3(float f) {
  unsigned u = __builtin_bit_cast(unsigned, f);
  unsigned s = (u >> 24) & 0x80u;
  unsigned a = u & 0x7FFFFFFFu;
  float af = __builtin_bit_cast(float, a);
  if (af < 0.015625f) {                    // below min normal 2^-6
    int m = (int)rintf(af * 512.0f);       // RNE; 8 naturally -> 2^-6 normal
    return (unsigned char)(s | (unsigned)m);
  }
  unsigned u2 = a + 0x0007FFFFu + ((a >> 20) & 1u);  // RNE to 3-bit mantissa
  int e = (int)(u2 >> 23) - 127 + 7;
  unsigned m = (u2 >> 20) & 7u;
  if (e > 15) return (unsigned char)(s | 0x7Eu);     // clamp to 448
  return (unsigned char)(s | ((unsigned)e << 3) | m);
}

// Order-preserving f32 -> u32.
__device__ __forceinline__ unsigned int mono_f32(float f) {
  unsigned int u = __builtin_bit_cast(unsigned int, f);
  return (u & 0x80000000u) ? ~u : (u | 0x80000000u);
}

__global__ void cvt_fp8_kernel(const float* __restrict__ x,
                               unsigned char* __restrict__ xq,
                               unsigned long long* __restrict__ nn64) {
  int i = blockIdx.x * blockDim.x + threadIdx.x;     // 8 elems per thread
  const float4* xp = reinterpret_cast<const float4*>(x) + 2 * (size_t)i;
  float4 v0 = xp[0], v1 = xp[1];
  unsigned long long w =
      (unsigned long long)f32_to_e4m3(v0.x) |
      ((unsigned long long)f32_to_e4m3(v0.y) << 8) |
      ((unsigned long long)f32_to_e4m3(v0.z) << 16) |
      ((unsigned long long)f32_to_e4m3(v0.w) << 24) |
      ((unsigned long long)f32_to_e4m3(v1.x) << 32) |
      ((unsigned long long)f32_to_e4m3(v1.y) << 40) |
      ((unsigned long long)f32_to_e4m3(v1.z) << 48) |
      ((unsigned long long)f32_to_e4m3(v1.w) << 56);
  reinterpret_cast<unsigned long long*>(xq)[i] = w;
  if (i < NPTS) nn64[i] = 0ull;
}

__device__ __forceinline__ void gload_lds16(const unsigned char* g,
                                            unsigned char* l) {
  __builtin_amdgcn_global_load_lds(
      (__attribute__((address_space(1))) const void*)g,
      (__attribute__((address_space(3))) void*)l, 16, 0, 0);
}

__device__ __forceinline__ unsigned long long kmax(unsigned long long a,
                                                   unsigned long long b) {
  return a > b ? a : b;
}

// Triangular fused fp8 GEMM + dual argmax.
// grid = NBLK, block = 256 (4 waves, 2x2 grid of 64x64 sub-tiles).
// LDS: A 32 KB + B 32 KB (one K-half) = 64 KB -> 2 blocks/CU.
__global__ __launch_bounds__(256, 2) void tri_gemm_kernel(
    const unsigned char* __restrict__ xq,
    unsigned long long* __restrict__ nn64) {
  __shared__ unsigned char lds[65536];

  // XCD-bijective swizzle (2080 = 8*260), then b -> (ti >= tj).
  const int orig = (int)blockIdx.x;
  int b = (orig & 7) * (NBLK >> 3) + (orig >> 3);
  int ti = (int)((sqrtf(8.0f * (float)b + 1.0f) - 1.0f) * 0.5f);
  while ((ti + 1) * (ti + 2) / 2 <= b) ++ti;
  while (ti * (ti + 1) / 2 > b) --ti;
  const int tj = b - ti * (ti + 1) / 2;

  const int tid  = (int)threadIdx.x;
  const int wid  = tid >> 6;
  const int lane = tid & 63;
  const int wr   = wid >> 1;      // 0..1
  const int wc   = wid & 1;       // 0..1
  const int l15  = lane & 15;
  const int l16  = lane >> 4;     // 0..3 (16B k-chunk index within 64B)
  const int arow0 = ti * BM;
  const int bcol0 = tj * BN;

  // Stage one K-half (h = 0,1): 4 ktiles x 128 rows x 64 B per operand.
  // Row = 4 slots of 16 B; LDS slot s of row r holds global 16B chunk
  // (s - ((r>>1)&3)) & 3  (rotation; proven conflict-free in round 6).
#define STAGE(h) do {                                                        \
    _Pragma("unroll")                                                        \
    for (int kt_ = 0; kt_ < 4; ++kt_) {                                      \
      _Pragma("unroll")                                                      \
      for (int i_ = 0; i_ < 2; ++i_) {                                       \
        const int chunk_ = (i_ << 8) + tid;          /* 0..511 */            \
        const int row_   = chunk_ >> 2;              /* 0..127 */            \
        const int c_     = ((chunk_ & 3) - ((row_ >> 1) & 3)) & 3;           \
        const size_t go_ = (h) * 256 + kt_ * 64 + (c_ << 4);                 \
        gload_lds16(xq + (size_t)(arow0 + row_) * DIM + go_,                 \
                    &lds[kt_ * 8192 + (chunk_ << 4)]);                        \
        gload_lds16(xq + (size_t)(bcol0 + row_) * DIM + go_,                 \
                    &lds[32768 + kt_ * 8192 + (chunk_ << 4)]);                \
      }                                                                      \
    }                                                                        \
  } while (0)

  // Fragment read offsets (within a ktile): lane row r = band + l15 reads
  // stored slot (l16 + rot) & 3, rot = (r>>1)&3 = (l15>>1)&3.
  const int rot = (l15 >> 1) & 3;
  int aoff[4], boff[4];
#pragma unroll
  for (int mi = 0; mi < 4; ++mi)
    aoff[mi] = (wr * 64 + mi * 16 + l15) * 64 + (((l16 + rot) & 3) << 4);
#pragma unroll
  for (int ni = 0; ni < 4; ++ni)
    boff[ni] = 32768 + (wc * 64 + ni * 16 + l15) * 64 + (((l16 + rot) & 3) << 4);

  f32x4 acc[4][4];
#pragma unroll
  for (int mi = 0; mi < 4; ++mi)
#pragma unroll
    for (int ni = 0; ni < 4; ++ni)
      acc[mi][ni] = (f32x4){0.f, 0.f, 0.f, 0.f};

  lx2 af[4][4], bf[4][4];   // [ktile][frag] — all compile-time indexed

#define LOAD_FRAGS() do {                                                    \
    _Pragma("unroll")                                                        \
    for (int kt_ = 0; kt_ < 4; ++kt_) {                                      \
      _Pragma("unroll")                                                      \
      for (int mi_ = 0; mi_ < 4; ++mi_)                                      \
        af[kt_][mi_] =                                                       \
            *reinterpret_cast<const lx2*>(&lds[kt_ * 8192 + aoff[mi_]]);     \
      _Pragma("unroll")                                                      \
      for (int ni_ = 0; ni_ < 4; ++ni_)                                      \
        bf[kt_][ni_] =                                                       \
            *reinterpret_cast<const lx2*>(&lds[kt_ * 8192 + boff[ni_]]);     \
    }                                                                        \
  } while (0)

#define COMPUTE() do {                                                       \
    __builtin_amdgcn_s_setprio(1);                                           \
    _Pragma("unroll")                                                        \
    for (int kt_ = 0; kt_ < 4; ++kt_)                                        \
      _Pragma("unroll")                                                      \
      for (int mi_ = 0; mi_ < 4; ++mi_)                                      \
        _Pragma("unroll")                                                    \
        for (int ni_ = 0; ni_ < 4; ++ni_) {                                  \
          acc[mi_][ni_] = __builtin_amdgcn_mfma_f32_16x16x32_fp8_fp8(        \
              af[kt_][mi_][0], bf[kt_][ni_][0], acc[mi_][ni_], 0, 0, 0);     \
          acc[mi_][ni_] = __builtin_amdgcn_mfma_f32_16x16x32_fp8_fp8(        \
              af[kt_][mi_][1], bf[kt_][ni_][1], acc[mi_][ni_], 0, 0, 0);     \
        }                                                                    \
    __builtin_amdgcn_s_setprio(0);                                           \
  } while (0)

  STAGE(0);                                           // 16 loads in flight
  asm volatile("s_waitcnt vmcnt(0)" ::: "memory");
  asm volatile("s_barrier" ::: "memory");             // half-0 visible

  LOAD_FRAGS();                                       // 32 ds_read_b128
  __syncthreads();          // lgkm drained + all waves done reading buffer

  STAGE(1);                 // overwrite safe; latency covered by MFMAs below
  COMPUTE();                // 128 MFMAs (half 0)

  asm volatile("s_waitcnt vmcnt(0)" ::: "memory");
  asm volatile("s_barrier" ::: "memory");             // half-1 visible

  LOAD_FRAGS();
  COMPUTE();                // 128 MFMAs (half 1)

#undef STAGE
#undef LOAD_FRAGS
#undef COMPUTE

  // ---- Epilogue: dual argmax. C/D layout: col=lane&15, row=(lane>>4)*4+reg.
  // Key = mono(v)<<32 | ~idx  (atomicMax => exact first-occurrence ties).

  // Row side: per output row, max over this wave's 64 columns.
#pragma unroll
  for (int mi = 0; mi < 4; ++mi)
#pragma unroll
    for (int j = 0; j < 4; ++j) {
      const int gi = arow0 + wr * 64 + mi * 16 + l16 * 4 + j;
      unsigned long long key = 0ull;
#pragma unroll
      for (int ni = 0; ni < 4; ++ni) {
        const int gj = bcol0 + wc * 64 + ni * 16 + l15;
        if (gi != gj) {
          unsigned long long k =
              ((unsigned long long)mono_f32(acc[mi][ni][j]) << 32) |
              (unsigned int)(~gj);
          key = kmax(key, k);
        }
      }
#pragma unroll
      for (int m = 1; m < 16; m <<= 1)
        key = kmax(key, __shfl_xor(key, m));
      if (l15 == 0) atomicMax(&nn64[gi], key);
    }

  // Col side (symmetry): per output col, max over this wave's 64 rows.
#pragma unroll
  for (int ni = 0; ni < 4; ++ni) {
    const int gj = bcol0 + wc * 64 + ni * 16 + l15;
    unsigned long long key = 0ull;
#pragma unroll
    for (int mi = 0; mi < 4; ++mi)
#pragma unroll
      for (int j = 0; j < 4; ++j) {
        const int gi = arow0 + wr * 64 + mi * 16 + l16 * 4 + j;
        if (gi != gj) {
          unsigned long long k =
              ((unsigned long long)mono_f32(acc[mi][ni][j]) << 32) |
              (unsigned int)(~gi);
          key = kmax(key, k);
        }
      }
#pragma unroll
    for (int m = 16; m < 64; m <<= 1)
      key = kmax(key, __shfl_xor(key, m));
    if (l16 == 0) atomicMax(&nn64[gj], key);
  }
}

// rho_r = ||x_r - x_{nn(r)} + 1e-6||_2 ; logs[r] = log(rho + 1e-8).
__global__ void dist_log_kernel(const float* __restrict__ x,
                                const unsigned long long* __restrict__ nn64,
                                float* __restrict__ logs) {
  const int row  = blockIdx.x * 4 + ((int)threadIdx.x >> 6);
  const int lane = (int)threadIdx.x & 63;
  const int nn   = (int)(~(unsigned int)(nn64[row] & 0xFFFFFFFFull)) & (NPTS - 1);
  const float4* xr = reinterpret_cast<const float4*>(x + (size_t)row * DIM);
  const float4* xn = reinterpret_cast<const float4*>(x + (size_t)nn  * DIM);
  float s = 0.f;
#pragma unroll
  for (int i = 0; i < 2; ++i) {
    float4 a = xr[lane + i * 64];
    float4 b = xn[lane + i * 64];
    float d0 = a.x - b.x + 1e-6f;
    float d1 = a.y - b.y + 1e-6f;
    float d2 = a.z - b.z + 1e-6f;
    float d3 = a.w - b.w + 1e-6f;
    s += d0 * d0 + d1 * d1 + d2 * d2 + d3 * d3;
  }
#pragma unroll
  for (int m = 32; m >= 1; m >>= 1) s += __shfl_xor(s, m);
  if (lane == 0) logs[row] = logf(sqrtf(s) + 1e-8f);
}

// Deterministic mean: 1024 threads x 8 sequential adds + LDS tree.
__global__ void final_reduce_kernel(const float* __restrict__ logs,
                                    float* __restrict__ out) {
  __shared__ float sm[1024];
  const int t = (int)threadIdx.x;
  float s = 0.f;
#pragma unroll
  for (int i = 0; i < 8; ++i) s += logs[t * 8 + i];
  sm[t] = s;
  __syncthreads();
  for (int k = 512; k > 0; k >>= 1) {
    if (t < k) sm[t] += sm[t + k];
    __syncthreads();
  }
  if (t == 0) out[0] = -(sm[0] / (float)NPTS);
}

extern "C" void kernel_launch(void* const* d_in, const int* in_sizes, int n_in,
                              void* d_out, int out_size, void* d_ws, size_t ws_size,
                              hipStream_t stream) {
  const float* x = (const float*)d_in[0];
  float* out = (float*)d_out;
  char* ws = (char*)d_ws;

  // Workspace layout (bytes):
  unsigned char*      xq   = (unsigned char*)(ws);                // 4 MB
  unsigned long long* nn64 = (unsigned long long*)(ws + 4194304); // 64 KB
  float*              logs = (float*)(ws + 4259840);              // 32 KB

  cvt_fp8_kernel<<<(NPTS * DIM / 8) / 256, 256, 0, stream>>>(x, xq, nn64);

  tri_gemm_kernel<<<NBLK, 256, 0, stream>>>(xq, nn64);

  dist_log_kernel<<<NPTS / 4, 256, 0, stream>>>(x, nn64, logs);

  final_reduce_kernel<<<1, 1024, 0, stream>>>(logs, out);
}

// Round 8
// 82.502 us; speedup vs baseline: 1.2226x; 1.2226x over previous
//
#include <hip/hip_runtime.h>

// n = 8192 points, d = 512, fp32 in, scalar fp32 out.
// Pipeline:
//   (1) fp32 -> fp8 e4m3 convert (+ zero-init packed argmax keys)
//   (2) triangular fused fp8-MFMA GEMM, m201-style phase schedule:
//       256x128 tiles, BK=64, 8 waves (4x2 of 64x64), double-buffered LDS,
//       4 phases per K-tile pair: {vmcnt(3); bar; ds_read x8; 16 MFMA} /
//       {lgkm0; bar; stage-next x3; 16 MFMA}. Loads never drained mid-loop.
//       Dual row/col argmax via u64 atomicMax of (mono(value)<<32 | ~index).
//   (3) per-row ||x - x[I] + 1e-6||_2 -> log   (full fp32)
//   (4) deterministic mean reduce.

#define NPTS 8192
#define DIM  512
#define BM   256
#define BN   128
#define NROWT 32
#define NBLK  1056    // sum_{ti<32}(2ti+2) = 32*33, = 8*132

typedef float f32x4 __attribute__((ext_vector_type(4)));
typedef long  lx2   __attribute__((ext_vector_type(2)));   // 16 B

// f32 -> OCP e4m3fn, round-to-nearest-even; N(0,1) data never clamps.
__device__ __forceinline__ unsigned char f32_to_e4m3(float f) {
  unsigned u = __builtin_bit_cast(unsigned, f);
  unsigned s = (u >> 24) & 0x80u;
  unsigned a = u & 0x7FFFFFFFu;
  float af = __builtin_bit_cast(float, a);
  if (af < 0.015625f) {                    // below min normal 2^-6
    int m = (int)rintf(af * 512.0f);       // RNE; 8 naturally -> 2^-6 normal
    return (unsigned char)(s | (unsigned)m);
  }
  unsigned u2 = a + 0x0007FFFFu + ((a >> 20) & 1u);  // RNE to 3-bit mantissa
  int e = (int)(u2 >> 23) - 127 + 7;
  unsigned m = (u2 >> 20) & 7u;
  if (e > 15) return (unsigned char)(s | 0x7Eu);     // clamp to 448
  return (unsigned char)(s | ((unsigned)e << 3) | m);
}

// Order-preserving f32 -> u32.
__device__ __forceinline__ unsigned int mono_f32(float f) {
  unsigned int u = __builtin_bit_cast(unsigned int, f);
  return (u & 0x80000000u) ? ~u : (u | 0x80000000u);
}

__global__ void cvt_fp8_kernel(const float* __restrict__ x,
                               unsigned char* __restrict__ xq,
                               unsigned long long* __restrict__ nn64) {
  int i = blockIdx.x * blockDim.x + threadIdx.x;     // 8 elems per thread
  const float4* xp = reinterpret_cast<const float4*>(x) + 2 * (size_t)i;
  float4 v0 = xp[0], v1 = xp[1];
  unsigned long long w =
      (unsigned long long)f32_to_e4m3(v0.x) |
      ((unsigned long long)f32_to_e4m3(v0.y) << 8) |
      ((unsigned long long)f32_to_e4m3(v0.z) << 16) |
      ((unsigned long long)f32_to_e4m3(v0.w) << 24) |
      ((unsigned long long)f32_to_e4m3(v1.x) << 32) |
      ((unsigned long long)f32_to_e4m3(v1.y) << 40) |
      ((unsigned long long)f32_to_e4m3(v1.z) << 48) |
      ((unsigned long long)f32_to_e4m3(v1.w) << 56);
  reinterpret_cast<unsigned long long*>(xq)[i] = w;
  if (i < NPTS) nn64[i] = 0ull;
}

__device__ __forceinline__ void gload_lds16(const unsigned char* g,
                                            unsigned char* l) {
  __builtin_amdgcn_global_load_lds(
      (__attribute__((address_space(1))) const void*)g,
      (__attribute__((address_space(3))) void*)l, 16, 0, 0);
}

__device__ __forceinline__ unsigned long long kmax(unsigned long long a,
                                                   unsigned long long b) {
  return a > b ? a : b;
}

// Triangular fused fp8 GEMM + dual argmax.
// grid = NBLK, block = 512 (8 waves, 4x2 grid of 64x64 sub-tiles).
// LDS: 2 buffers x (A 16KB + B 8KB) = 48 KB.
__global__ __launch_bounds__(512, 2) void tri_gemm_kernel(
    const unsigned char* __restrict__ xq,
    unsigned long long* __restrict__ nn64) {
  __shared__ unsigned char lds[2][24576];

  // Bijective XCD swizzle (1056 = 8*132), then b -> (ti, tj):
  // cum(ti) = ti*(ti+1), tj in [0, 2ti+2).
  const int orig = (int)blockIdx.x;
  int b = (orig & 7) * (NBLK >> 3) + (orig >> 3);
  int ti = (int)((sqrtf(4.0f * (float)b + 1.0f) - 1.0f) * 0.5f);
  while ((ti + 1) * (ti + 2) <= b) ++ti;
  while (ti * (ti + 1) > b) --ti;
  const int tj = b - ti * (ti + 1);

  const int tid  = (int)threadIdx.x;
  const int wid  = tid >> 6;
  const int lane = tid & 63;
  const int wr   = wid >> 1;      // 0..3  (64-row band within 256)
  const int wc   = wid & 1;       // 0..1  (64-col band within 128)
  const int l15  = lane & 15;
  const int l16  = lane >> 4;     // 0..3 (16B k-chunk index within 64B row)
  const int arow0 = ti * BM;
  const int bcol0 = tj * BN;

  // Staging per K-tile: A = 1024 16B-chunks (2/thread), B = 512 (1/thread).
  // Row = 4 slots of 16B; LDS slot s of row r holds global chunk
  // (s - ((r>>1)&3)) & 3  (rotation; proven conflict-free with b128 reads).
  const int arow_s0 = tid >> 2;                 // A chunk tid
  const int ac0 = ((tid & 3) - ((arow_s0 >> 1) & 3)) & 3;
  const int arow_s1 = (tid + 512) >> 2;         // A chunk tid+512
  const int ac1 = ((tid & 3) - ((arow_s1 >> 1) & 3)) & 3;
  const unsigned char* gA0 = xq + (size_t)(arow0 + arow_s0) * DIM + (ac0 << 4);
  const unsigned char* gA1 = xq + (size_t)(arow0 + arow_s1) * DIM + (ac1 << 4);
  const unsigned char* gB0 = xq + (size_t)(bcol0 + arow_s0) * DIM + (ac0 << 4);

#define STAGE(bufi, kt) do {                                                 \
    gload_lds16(gA0 + (kt) * 64, &lds[bufi][tid << 4]);                      \
    gload_lds16(gA1 + (kt) * 64, &lds[bufi][(tid + 512) << 4]);              \
    gload_lds16(gB0 + (kt) * 64, &lds[bufi][16384 + (tid << 4)]);            \
  } while (0)

  // Fragment reads: lane row r = band + l15 reads stored b128 slot
  // (l16 + rot) & 3, rot = (r>>1)&3 = (l15>>1)&3 (bands are x16).
  const int rot = (l15 >> 1) & 3;
  int aoff[4], boff[4];
#pragma unroll
  for (int mi = 0; mi < 4; ++mi)
    aoff[mi] = (wr * 64 + mi * 16 + l15) * 64 + (((l16 + rot) & 3) << 4);
#pragma unroll
  for (int ni = 0; ni < 4; ++ni)
    boff[ni] = 16384 + (wc * 64 + ni * 16 + l15) * 64 + (((l16 + rot) & 3) << 4);

  f32x4 acc[4][4];
#pragma unroll
  for (int mi = 0; mi < 4; ++mi)
#pragma unroll
    for (int ni = 0; ni < 4; ++ni)
      acc[mi][ni] = (f32x4){0.f, 0.f, 0.f, 0.f};

  lx2 a2[4], b2[4];

#define READ_FRAGS(bufi) do {                                                \
    _Pragma("unroll")                                                        \
    for (int mi_ = 0; mi_ < 4; ++mi_)                                        \
      a2[mi_] = *reinterpret_cast<const lx2*>(&lds[bufi][aoff[mi_]]);        \
    _Pragma("unroll")                                                        \
    for (int ni_ = 0; ni_ < 4; ++ni_)                                        \
      b2[ni_] = *reinterpret_cast<const lx2*>(&lds[bufi][boff[ni_]]);        \
  } while (0)

#define MFMA_HALF(kk) do {                                                   \
    __builtin_amdgcn_s_setprio(1);                                           \
    _Pragma("unroll")                                                        \
    for (int mi_ = 0; mi_ < 4; ++mi_)                                        \
      _Pragma("unroll")                                                      \
      for (int ni_ = 0; ni_ < 4; ++ni_)                                      \
        acc[mi_][ni_] = __builtin_amdgcn_mfma_f32_16x16x32_fp8_fp8(          \
            a2[mi_][kk], b2[ni_][kk], acc[mi_][ni_], 0, 0, 0);               \
    __builtin_amdgcn_s_setprio(0);                                           \
  } while (0)

  // Prologue: stage K-tiles 0 and 1 (6 loads in flight).
  STAGE(0, 0);
  STAGE(1, 1);

  for (int p = 0; p < 4; ++p) {
    // ---- P0: consume tile 2p (buf0), kk=0.
    asm volatile("s_waitcnt vmcnt(3)" ::: "memory");  // tile 2p's 3 landed
    asm volatile("s_barrier" ::: "memory");           // buf0 published
    READ_FRAGS(0);
    MFMA_HALF(0);

    // ---- P1: free buf0, stage tile 2p+2, compute kk=1 from regs.
    asm volatile("s_waitcnt lgkmcnt(0)" ::: "memory");
    asm volatile("s_barrier" ::: "memory");           // all reads of buf0 done
    if (p < 3) STAGE(0, 2 * p + 2);                   // in flight: 3 + 3
    MFMA_HALF(1);

    // ---- P2: consume tile 2p+1 (buf1), kk=0.
    if (p < 3) {
      asm volatile("s_waitcnt vmcnt(3)" ::: "memory"); // tile 2p+1 landed
    } else {
      asm volatile("s_waitcnt vmcnt(0)" ::: "memory"); // last pair: drain
    }
    asm volatile("s_barrier" ::: "memory");           // buf1 published
    READ_FRAGS(1);
    MFMA_HALF(0);

    // ---- P3: free buf1, stage tile 2p+3, compute kk=1 from regs.
    asm volatile("s_waitcnt lgkmcnt(0)" ::: "memory");
    asm volatile("s_barrier" ::: "memory");           // all reads of buf1 done
    if (p < 3) STAGE(1, 2 * p + 3);                   // in flight: 3 + 3
    MFMA_HALF(1);
  }
#undef STAGE
#undef READ_FRAGS
#undef MFMA_HALF

  // ---- Epilogue: dual argmax. C/D layout: col=lane&15, row=(lane>>4)*4+reg.
  // Key = mono(v)<<32 | ~idx  (atomicMax => exact first-occurrence ties).

  // Row side: per output row, max over this wave's 64 columns.
#pragma unroll
  for (int mi = 0; mi < 4; ++mi)
#pragma unroll
    for (int j = 0; j < 4; ++j) {
      const int gi = arow0 + wr * 64 + mi * 16 + l16 * 4 + j;
      unsigned long long key = 0ull;
#pragma unroll
      for (int ni = 0; ni < 4; ++ni) {
        const int gj = bcol0 + wc * 64 + ni * 16 + l15;
        if (gi != gj) {
          unsigned long long k =
              ((unsigned long long)mono_f32(acc[mi][ni][j]) << 32) |
              (unsigned int)(~gj);
          key = kmax(key, k);
        }
      }
#pragma unroll
      for (int m = 1; m < 16; m <<= 1)
        key = kmax(key, __shfl_xor(key, m));
      if (l15 == 0) atomicMax(&nn64[gi], key);
    }

  // Col side (symmetry): per output col, max over this wave's 64 rows.
#pragma unroll
  for (int ni = 0; ni < 4; ++ni) {
    const int gj = bcol0 + wc * 64 + ni * 16 + l15;
    unsigned long long key = 0ull;
#pragma unroll
    for (int mi = 0; mi < 4; ++mi)
#pragma unroll
      for (int j = 0; j < 4; ++j) {
        const int gi = arow0 + wr * 64 + mi * 16 + l16 * 4 + j;
        if (gi != gj) {
          unsigned long long k =
              ((unsigned long long)mono_f32(acc[mi][ni][j]) << 32) |
              (unsigned int)(~gi);
          key = kmax(key, k);
        }
      }
#pragma unroll
    for (int m = 16; m < 64; m <<= 1)
      key = kmax(key, __shfl_xor(key, m));
    if (l16 == 0) atomicMax(&nn64[gj], key);
  }
}

// rho_r = ||x_r - x_{nn(r)} + 1e-6||_2 ; logs[r] = log(rho + 1e-8).
__global__ void dist_log_kernel(const float* __restrict__ x,
                                const unsigned long long* __restrict__ nn64,
                                float* __restrict__ logs) {
  const int row  = blockIdx.x * 4 + ((int)threadIdx.x >> 6);
  const int lane = (int)threadIdx.x & 63;
  const int nn   = (int)(~(unsigned int)(nn64[row] & 0xFFFFFFFFull)) & (NPTS - 1);
  const float4* xr = reinterpret_cast<const float4*>(x + (size_t)row * DIM);
  const float4* xn = reinterpret_cast<const float4*>(x + (size_t)nn  * DIM);
  float s = 0.f;
#pragma unroll
  for (int i = 0; i < 2; ++i) {
    float4 a = xr[lane + i * 64];
    float4 b = xn[lane + i * 64];
    float d0 = a.x - b.x + 1e-6f;
    float d1 = a.y - b.y + 1e-6f;
    float d2 = a.z - b.z + 1e-6f;
    float d3 = a.w - b.w + 1e-6f;
    s += d0 * d0 + d1 * d1 + d2 * d2 + d3 * d3;
  }
#pragma unroll
  for (int m = 32; m >= 1; m >>= 1) s += __shfl_xor(s, m);
  if (lane == 0) logs[row] = logf(sqrtf(s) + 1e-8f);
}

// Deterministic mean: 1024 threads x 8 sequential adds + LDS tree.
__global__ void final_reduce_kernel(const float* __restrict__ logs,
                                    float* __restrict__ out) {
  __shared__ float sm[1024];
  const int t = (int)threadIdx.x;
  float s = 0.f;
#pragma unroll
  for (int i = 0; i < 8; ++i) s += logs[t * 8 + i];
  sm[t] = s;
  __syncthreads();
  for (int k = 512; k > 0; k >>= 1) {
    if (t < k) sm[t] += sm[t + k];
    __syncthreads();
  }
  if (t == 0) out[0] = -(sm[0] / (float)NPTS);
}

extern "C" void kernel_launch(void* const* d_in, const int* in_sizes, int n_in,
                              void* d_out, int out_size, void* d_ws, size_t ws_size,
                              hipStream_t stream) {
  const float* x = (const float*)d_in[0];
  float* out = (float*)d_out;
  char* ws = (char*)d_ws;

  // Workspace layout (bytes):
  unsigned char*      xq   = (unsigned char*)(ws);                // 4 MB
  unsigned long long* nn64 = (unsigned long long*)(ws + 4194304); // 64 KB
  float*              logs = (float*)(ws + 4259840);              // 32 KB

  cvt_fp8_kernel<<<(NPTS * DIM / 8) / 256, 256, 0, stream>>>(x, xq, nn64);

  tri_gemm_kernel<<<NBLK, 512, 0, stream>>>(xq, nn64);

  dist_log_kernel<<<NPTS / 4, 256, 0, stream>>>(x, nn64, logs);

  final_reduce_kernel<<<1, 1024, 0, stream>>>(logs, out);
}

// Round 9
// 49.697 us; speedup vs baseline: 2.0297x; 1.6601x over previous
//
#include <hip/hip_runtime.h>

// n = 8192 points, d = 512, fp32 in, scalar fp32 out.
// Pipeline:
//   (1) fp32 -> fp8 e4m3 convert (+ zero-init packed argmax keys)
//   (2) triangular fused fp8-MFMA GEMM: 128x128 tiles, BK=64 rotation layout,
//       3-buffer LDS, ONE barrier per K-tile, depth-2 counted-vmcnt staging.
//       Dual row/col argmax with butterfly slot-merge reduction (15+3
//       shuffle-steps, 2 atomic instructions per wave) via u64 keys
//       (mono(value)<<32 | ~index) -> exact first-occurrence ties.
//   (3) per-row ||x - x[I] + 1e-6||_2 -> log   (full fp32)
//   (4) deterministic mean reduce.

#define NPTS 8192
#define DIM  512
#define BM   128
#define BN   128
#define NTIL 64
#define NBLK (NTIL * (NTIL + 1) / 2)   // 2080 (= 8*260, XCD-divisible)
#define KT_N 8                          // 512 / 64

typedef float f32x4 __attribute__((ext_vector_type(4)));
typedef long  lx2   __attribute__((ext_vector_type(2)));   // 16 B

// f32 -> OCP e4m3fn, round-to-nearest-even; N(0,1) data never clamps.
__device__ __forceinline__ unsigned char f32_to_e4m3(float f) {
  unsigned u = __builtin_bit_cast(unsigned, f);
  unsigned s = (u >> 24) & 0x80u;
  unsigned a = u & 0x7FFFFFFFu;
  float af = __builtin_bit_cast(float, a);
  if (af < 0.015625f) {                    // below min normal 2^-6
    int m = (int)rintf(af * 512.0f);       // RNE; 8 naturally -> 2^-6 normal
    return (unsigned char)(s | (unsigned)m);
  }
  unsigned u2 = a + 0x0007FFFFu + ((a >> 20) & 1u);  // RNE to 3-bit mantissa
  int e = (int)(u2 >> 23) - 127 + 7;
  unsigned m = (u2 >> 20) & 7u;
  if (e > 15) return (unsigned char)(s | 0x7Eu);     // clamp to 448
  return (unsigned char)(s | ((unsigned)e << 3) | m);
}

// Order-preserving f32 -> u32 (branchless: 3 VALU).
__device__ __forceinline__ unsigned int mono_f32(float f) {
  unsigned u = __builtin_bit_cast(unsigned, f);
  return u ^ (0x80000000u | (unsigned)((int)u >> 31));
}

__global__ void cvt_fp8_kernel(const float* __restrict__ x,
                               unsigned char* __restrict__ xq,
                               unsigned long long* __restrict__ nn64) {
  int i = blockIdx.x * blockDim.x + threadIdx.x;     // 8 elems per thread
  const float4* xp = reinterpret_cast<const float4*>(x) + 2 * (size_t)i;
  float4 v0 = xp[0], v1 = xp[1];
  unsigned long long w =
      (unsigned long long)f32_to_e4m3(v0.x) |
      ((unsigned long long)f32_to_e4m3(v0.y) << 8) |
      ((unsigned long long)f32_to_e4m3(v0.z) << 16) |
      ((unsigned long long)f32_to_e4m3(v0.w) << 24) |
      ((unsigned long long)f32_to_e4m3(v1.x) << 32) |
      ((unsigned long long)f32_to_e4m3(v1.y) << 40) |
      ((unsigned long long)f32_to_e4m3(v1.z) << 48) |
      ((unsigned long long)f32_to_e4m3(v1.w) << 56);
  reinterpret_cast<unsigned long long*>(xq)[i] = w;
  if (i < NPTS) nn64[i] = 0ull;
}

__device__ __forceinline__ void gload_lds16(const unsigned char* g,
                                            unsigned char* l) {
  __builtin_amdgcn_global_load_lds(
      (__attribute__((address_space(1))) const void*)g,
      (__attribute__((address_space(3))) void*)l, 16, 0, 0);
}

__device__ __forceinline__ unsigned long long kmax(unsigned long long a,
                                                   unsigned long long b) {
  return a > b ? a : b;
}

// Triangular fused fp8 GEMM + dual argmax.
// grid = NBLK, block = 256 (4 waves, 2x2 grid of 64x64 sub-tiles).
// LDS: 3 buffers x (A 8KB + B 8KB) = 48 KB -> 3 blocks/CU.
__global__ __launch_bounds__(256, 3) void tri_gemm_kernel(
    const unsigned char* __restrict__ xq,
    unsigned long long* __restrict__ nn64) {
  __shared__ unsigned char lds[3][16384];

  // XCD-bijective swizzle (2080 = 8*260), then b -> (ti >= tj).
  const int orig = (int)blockIdx.x;
  int b = (orig & 7) * (NBLK >> 3) + (orig >> 3);
  int ti = (int)((sqrtf(8.0f * (float)b + 1.0f) - 1.0f) * 0.5f);
  while ((ti + 1) * (ti + 2) / 2 <= b) ++ti;
  while (ti * (ti + 1) / 2 > b) --ti;
  const int tj = b - ti * (ti + 1) / 2;

  const int tid  = (int)threadIdx.x;
  const int wid  = tid >> 6;
  const int lane = tid & 63;
  const int wr   = wid >> 1;      // 0..1
  const int wc   = wid & 1;       // 0..1
  const int l15  = lane & 15;
  const int l16  = lane >> 4;     // 0..3
  const int arow0 = ti * BM;
  const int bcol0 = tj * BN;

  // Staging: row = 64 B = 4 slots of 16 B. LDS slot s of row r holds global
  // chunk (s - ((r>>1)&3)) & 3  (rotation; proven conflict-free, absmax 0.0).
#define STAGE(bufi, kt) do {                                                 \
    _Pragma("unroll")                                                        \
    for (int i_ = 0; i_ < 2; ++i_) {                                         \
      const int chunk_ = (i_ << 8) + tid;          /* 0..511 */              \
      const int row_   = chunk_ >> 2;              /* 0..127 */              \
      const int c_     = ((chunk_ & 3) - ((row_ >> 1) & 3)) & 3;             \
      gload_lds16(xq + (size_t)(arow0 + row_) * DIM + (kt) * 64 + (c_ << 4), \
                  &lds[bufi][chunk_ << 4]);                                   \
      gload_lds16(xq + (size_t)(bcol0 + row_) * DIM + (kt) * 64 + (c_ << 4), \
                  &lds[bufi][8192 + (chunk_ << 4)]);                          \
    }                                                                        \
  } while (0)

  // Fragment reads: lane row r = band + l15 reads stored b128 slot
  // (l16 + rot) & 3, rot = (r>>1)&3 = (l15>>1)&3 (bands are x16).
  const int rot = (l15 >> 1) & 3;
  int aoff[4], boff[4];
#pragma unroll
  for (int mi = 0; mi < 4; ++mi)
    aoff[mi] = (wr * 64 + mi * 16 + l15) * 64 + (((l16 + rot) & 3) << 4);
#pragma unroll
  for (int ni = 0; ni < 4; ++ni)
    boff[ni] = 8192 + (wc * 64 + ni * 16 + l15) * 64 + (((l16 + rot) & 3) << 4);

  f32x4 acc[4][4];
#pragma unroll
  for (int mi = 0; mi < 4; ++mi)
#pragma unroll
    for (int ni = 0; ni < 4; ++ni)
      acc[mi][ni] = (f32x4){0.f, 0.f, 0.f, 0.f};

  // Prologue: 2 K-tiles in flight (depth-2).
  STAGE(0, 0);
  STAGE(1, 1);

  // ONE barrier per K-tile: after bar(u), all waves' reads of tile u-1 are
  // retired (consumed by MFMAs before each wave re-arrived), so staging
  // tile u+2 into buf[(u+2)%3] (= tile u-1's buffer) is safe.
  for (int u = 0; u < KT_N; ++u) {
    const int cur = u - (u / 3) * 3;            // u % 3
    if (u == KT_N - 1) {
      asm volatile("s_waitcnt vmcnt(0)" ::: "memory");
    } else {
      asm volatile("s_waitcnt vmcnt(4)" ::: "memory");  // tile u landed
    }
    asm volatile("s_barrier" ::: "memory");             // buf[cur] published
    if (u + 2 < KT_N) {
      const int nb = (u + 2) - ((u + 2) / 3) * 3;
      STAGE(nb, u + 2);                                 // depth-2 prefetch
    }

    lx2 a2[4], b2[4];
#pragma unroll
    for (int mi = 0; mi < 4; ++mi)
      a2[mi] = *reinterpret_cast<const lx2*>(&lds[cur][aoff[mi]]);
#pragma unroll
    for (int ni = 0; ni < 4; ++ni)
      b2[ni] = *reinterpret_cast<const lx2*>(&lds[cur][boff[ni]]);
    __builtin_amdgcn_s_setprio(1);
#pragma unroll
    for (int mi = 0; mi < 4; ++mi)
#pragma unroll
      for (int ni = 0; ni < 4; ++ni) {
        acc[mi][ni] = __builtin_amdgcn_mfma_f32_16x16x32_fp8_fp8(
            a2[mi][0], b2[ni][0], acc[mi][ni], 0, 0, 0);
        acc[mi][ni] = __builtin_amdgcn_mfma_f32_16x16x32_fp8_fp8(
            a2[mi][1], b2[ni][1], acc[mi][ni], 0, 0, 0);
      }
    __builtin_amdgcn_s_setprio(0);
  }
#undef STAGE

  // ---- Epilogue: dual argmax via butterfly slot-merge.
  // C/D layout: col(gj)=l15, row(gi)=l16*4+reg. Key = mono(v)<<32 | ~idx.
  const bool diagw = (ti == tj) && (wr == wc);

  // Row side: 16 slots (mi*4+j), each pre-merged over ni.
  unsigned long long K[16];
  const unsigned jb = ~(unsigned)(bcol0 + wc * 64 + l15);
#pragma unroll
  for (int mi = 0; mi < 4; ++mi)
#pragma unroll
    for (int j = 0; j < 4; ++j) {
      unsigned long long best = 0ull;
#pragma unroll
      for (int ni = 0; ni < 4; ++ni) {
        unsigned long long kk =
            ((unsigned long long)mono_f32(acc[mi][ni][j]) << 32) |
            (unsigned)(jb - ni * 16);
        if (diagw && mi == ni && (l16 * 4 + j) == l15) kk = 0ull;
        best = kmax(best, kk);
      }
      K[mi * 4 + j] = best;
    }
  // Butterfly over l15 bits: slots halve each level; lane ends with slot
  // s = l15 fully reduced over its 16-lane group. 15 shuffle-steps total.
#pragma unroll
  for (int k = 0; k < 4; ++k) {
    const int m = 1 << k;
    const unsigned kb = (unsigned)(l15 >> k) & 1u;
#pragma unroll
    for (int i = 0; i < (8 >> k); ++i) {
      unsigned long long lo = K[2 * i], hi = K[2 * i + 1];
      unsigned long long keep = kb ? hi : lo;
      unsigned long long send = kb ? lo : hi;
      unsigned long long recv =
          (unsigned long long)__shfl_xor((long long)send, m);
      K[i] = kmax(keep, recv);
    }
  }
  {
    // slot s = l15: mi = l15>>2, j = l15&3; all 64 lanes distinct gi.
    const int gi = arow0 + wr * 64 + (l15 >> 2) * 16 + l16 * 4 + (l15 & 3);
    atomicMax(&nn64[gi], K[0]);
  }

  // Col side: 4 slots (ni), pre-merged over (mi, j); butterfly over l16 bits.
  unsigned long long C[4];
  const unsigned ib = ~(unsigned)(arow0 + wr * 64 + l16 * 4);
#pragma unroll
  for (int ni = 0; ni < 4; ++ni) {
    unsigned long long best = 0ull;
#pragma unroll
    for (int mi = 0; mi < 4; ++mi)
#pragma unroll
      for (int j = 0; j < 4; ++j) {
        unsigned long long kk =
            ((unsigned long long)mono_f32(acc[mi][ni][j]) << 32) |
            (unsigned)(ib - (mi * 16 + j));
        if (diagw && mi == ni && (l16 * 4 + j) == l15) kk = 0ull;
        best = kmax(best, kk);
      }
    C[ni] = best;
  }
#pragma unroll
  for (int k = 0; k < 2; ++k) {
    const int m = 16 << k;
    const unsigned kb = (unsigned)(lane >> (4 + k)) & 1u;
#pragma unroll
    for (int i = 0; i < (2 >> k); ++i) {
      unsigned long long lo = C[2 * i], hi = C[2 * i + 1];
      unsigned long long keep = kb ? hi : lo;
      unsigned long long send = kb ? lo : hi;
      unsigned long long recv =
          (unsigned long long)__shfl_xor((long long)send, m);
      C[i] = kmax(keep, recv);
    }
  }
  {
    // slot ni = l16: gj = bcol0 + wc*64 + l16*16 + l15; 64 distinct gj.
    const int gj = bcol0 + wc * 64 + l16 * 16 + l15;
    atomicMax(&nn64[gj], C[0]);
  }
}

// rho_r = ||x_r - x_{nn(r)} + 1e-6||_2 ; logs[r] = log(rho + 1e-8).
__global__ void dist_log_kernel(const float* __restrict__ x,
                                const unsigned long long* __restrict__ nn64,
                                float* __restrict__ logs) {
  const int row  = blockIdx.x * 4 + ((int)threadIdx.x >> 6);
  const int lane = (int)threadIdx.x & 63;
  const int nn   = (int)(~(unsigned int)(nn64[row] & 0xFFFFFFFFull)) & (NPTS - 1);
  const float4* xr = reinterpret_cast<const float4*>(x + (size_t)row * DIM);
  const float4* xn = reinterpret_cast<const float4*>(x + (size_t)nn  * DIM);
  float s = 0.f;
#pragma unroll
  for (int i = 0; i < 2; ++i) {
    float4 a = xr[lane + i * 64];
    float4 b = xn[lane + i * 64];
    float d0 = a.x - b.x + 1e-6f;
    float d1 = a.y - b.y + 1e-6f;
    float d2 = a.z - b.z + 1e-6f;
    float d3 = a.w - b.w + 1e-6f;
    s += d0 * d0 + d1 * d1 + d2 * d2 + d3 * d3;
  }
#pragma unroll
  for (int m = 32; m >= 1; m >>= 1) s += __shfl_xor(s, m);
  if (lane == 0) logs[row] = logf(sqrtf(s) + 1e-8f);
}

// Deterministic mean: 1024 threads x 8 sequential adds + LDS tree.
__global__ void final_reduce_kernel(const float* __restrict__ logs,
                                    float* __restrict__ out) {
  __shared__ float sm[1024];
  const int t = (int)threadIdx.x;
  float s = 0.f;
#pragma unroll
  for (int i = 0; i < 8; ++i) s += logs[t * 8 + i];
  sm[t] = s;
  __syncthreads();
  for (int k = 512; k > 0; k >>= 1) {
    if (t < k) sm[t] += sm[t + k];
    __syncthreads();
  }
  if (t == 0) out[0] = -(sm[0] / (float)NPTS);
}

extern "C" void kernel_launch(void* const* d_in, const int* in_sizes, int n_in,
                              void* d_out, int out_size, void* d_ws, size_t ws_size,
                              hipStream_t stream) {
  const float* x = (const float*)d_in[0];
  float* out = (float*)d_out;
  char* ws = (char*)d_ws;

  // Workspace layout (bytes):
  unsigned char*      xq   = (unsigned char*)(ws);                // 4 MB
  unsigned long long* nn64 = (unsigned long long*)(ws + 4194304); // 64 KB
  float*              logs = (float*)(ws + 4259840);              // 32 KB

  cvt_fp8_kernel<<<(NPTS * DIM / 8) / 256, 256, 0, stream>>>(x, xq, nn64);

  tri_gemm_kernel<<<NBLK, 256, 0, stream>>>(xq, nn64);

  dist_log_kernel<<<NPTS / 4, 256, 0, stream>>>(x, nn64, logs);

  final_reduce_kernel<<<1, 1024, 0, stream>>>(logs, out);
}